// Round 1
// baseline (290.489 us; speedup 1.0000x reference)
//
#include <hip/hip_runtime.h>
#include <math.h>

#define HH 256
#define WW 256
#define CC 64
#define NB 8
#define ROWS 8
#define TW 32

typedef float fvec4 __attribute__((ext_vector_type(4)));
typedef float floatx4 __attribute__((ext_vector_type(4)));
typedef _Float16 half8 __attribute__((ext_vector_type(8)));

// ---------------------------------------------------------------------------
// Kernel 1: Mh[k][c] = f16( softmax(G) @ P @ softmax(A) )[k][c], row-major.
// ---------------------------------------------------------------------------
__global__ __launch_bounds__(1024) void prep_M(const float* __restrict__ A,
                                               const float* __restrict__ G,
                                               const float* __restrict__ P,
                                               _Float16* __restrict__ Mh) {
    __shared__ __align__(16) float As[64][68];
    __shared__ __align__(16) float Gs[64][68];
    __shared__ __align__(16) float T[64][68];

    const int t = threadIdx.x;
    const int wave = t >> 6;
    const int lane = t & 63;

    for (int r8 = 0; r8 < 8; ++r8) {
        int row = wave * 8 + r8;       // 0..127
        int r = row & 63;
        const float* src = (row < 64) ? A : G;
        float v = src[r * 64 + lane];
        float m = v;
        #pragma unroll
        for (int off = 32; off > 0; off >>= 1)
            m = fmaxf(m, __shfl_xor(m, off, 64));
        float e = __expf(v - m);
        float s = e;
        #pragma unroll
        for (int off = 32; off > 0; off >>= 1)
            s += __shfl_xor(s, off, 64);
        float o = e / s;
        if (row < 64) As[r][lane] = o; else Gs[r][lane] = o;
    }
    __syncthreads();

    // T = P @ As
    {
        const int d = t >> 4, q = t & 15;
        float4 acc = make_float4(0.f, 0.f, 0.f, 0.f);
        for (int e = 0; e < 64; ++e) {
            float p = P[d * 64 + e];
            float4 a = *(const float4*)&As[e][4 * q];
            acc.x = fmaf(p, a.x, acc.x);
            acc.y = fmaf(p, a.y, acc.y);
            acc.z = fmaf(p, a.z, acc.z);
            acc.w = fmaf(p, a.w, acc.w);
        }
        *(float4*)&T[d][4 * q] = acc;
    }
    __syncthreads();

    // M = Gs @ T ; store f16 row-major: Mh[k*64 + c]
    {
        const int k = t >> 4, q = t & 15;
        float4 acc = make_float4(0.f, 0.f, 0.f, 0.f);
        for (int d = 0; d < 64; ++d) {
            float g = Gs[k][d];
            float4 tv = *(const float4*)&T[d][4 * q];
            acc.x = fmaf(g, tv.x, acc.x);
            acc.y = fmaf(g, tv.y, acc.y);
            acc.z = fmaf(g, tv.z, acc.z);
            acc.w = fmaf(g, tv.w, acc.w);
        }
        _Float16* mp = Mh + k * 64 + 4 * q;
        mp[0] = (_Float16)acc.x;
        mp[1] = (_Float16)acc.y;
        mp[2] = (_Float16)acc.z;
        mp[3] = (_Float16)acc.w;
    }
}

// ---------------------------------------------------------------------------
// Kernel 2: strip-mined fused depthwise conv (fp32 VALU) + channel mix via
// mfma_f32_16x16x32_f16 with SWAPPED operands (A = dw tile, B = M), so the
// accumulator D is [w][k]: each lane's 4 regs are 4 consecutive w -> direct
// float4 nontemporal stores. W-tile shrunk 64->32 so LDS halves (17.4 KB)
// and 7-8 blocks/CU fit: 2048 blocks total for latency hiding / tail fill.
// One barrier per row; dwT double-buffered; rolling 3-row register prefetch.
// ---------------------------------------------------------------------------
__global__ __launch_bounds__(256, 7) void fused_conv_mix(const float* __restrict__ x,
                                                         const float* __restrict__ dwgt,
                                                         const _Float16* __restrict__ Mh,
                                                         float* __restrict__ out) {
    __shared__ __align__(16) float dwT[2][TW][68];   // [buf][w_local][c], 17.4 KB

    const int t = threadIdx.x;
    const int tw0 = blockIdx.x * TW;
    const int h0 = blockIdx.y * ROWS;
    const int b = blockIdx.z;

    // ---- conv persona: thread = (c, chunk of 8 w) ----
    const int c = t >> 2;
    const int chunk = t & 3;
    const int gw0 = tw0 + chunk * 8;
    const float* xc = x + ((size_t)(b * CC + c) * HH) * WW;

    float wg[9];
    #pragma unroll
    for (int i = 0; i < 9; ++i) wg[i] = dwgt[c * 9 + i];

    // ---- mix persona ----
    const int wave = t >> 6;          // k-block = wave*16
    const int lane = t & 63;
    const int q = lane >> 4;          // quad
    const int mrow = lane & 15;       // B col (k_out) ; A row (w within subtile)

    // B-fragments: M[k = wave*16 + mrow][c = s*32 + q*8 + j], j=0..7. Held all kernel.
    half8 af0, af1;
    {
        const half8* ap = (const half8*)(Mh + (wave * 16 + mrow) * 64);
        af0 = ap[q];          // c0 = q*8
        af1 = ap[4 + q];      // c0 = 32 + q*8
    }

    float rows[3][10];

    auto load_row = [&](float* r, int y) {
        if ((unsigned)y < (unsigned)HH) {
            const float* p = xc + y * WW + gw0;
            const float4* p4 = (const float4*)p;
            float4 v0 = p4[0], v1 = p4[1];
            r[1] = v0.x; r[2] = v0.y; r[3] = v0.z; r[4] = v0.w;
            r[5] = v1.x; r[6] = v1.y; r[7] = v1.z; r[8] = v1.w;
            r[0] = (gw0 > 0)      ? p[-1] : 0.f;
            r[9] = (gw0 + 8 < WW) ? p[8]  : 0.f;
        } else {
            #pragma unroll
            for (int i = 0; i < 10; ++i) r[i] = 0.f;
        }
    };

    load_row(rows[0], h0 - 1);
    load_row(rows[1], h0);
    load_row(rows[2], h0 + 1);

    // store base: channel k_out = wave*16 + mrow, w = tw0 + q*4 (sub adds +16)
    float* obase = out + (((size_t)(b * CC + wave * 16 + mrow)) * HH + h0) * WW + tw0 + q * 4;

    #pragma unroll
    for (int i = 0; i < ROWS; ++i) {
        const float* rm_ = rows[(i + 0) % 3];
        const float* r0_ = rows[(i + 1) % 3];
        const float* rp_ = rows[(i + 2) % 3];

        // ---- conv row h0+i -> dwT[i&1][w][c] (transposed) ----
        #pragma unroll
        for (int j = 0; j < 8; ++j) {
            float a = 0.f;
            #pragma unroll
            for (int dx = 0; dx < 3; ++dx) {
                a = fmaf(wg[0 * 3 + dx], rm_[j + dx], a);
                a = fmaf(wg[1 * 3 + dx], r0_[j + dx], a);
                a = fmaf(wg[2 * 3 + dx], rp_[j + dx], a);
            }
            dwT[i & 1][chunk * 8 + j][c] = a;
        }
        __syncthreads();

        // prefetch row h0+i+2 into the retiring buffer (register-renamed)
        if (i < ROWS - 1) load_row(rows[i % 3], h0 + i + 2);

        // ---- mix via MFMA: D[w][k] = sum_c dwT[w][c] * M[k][c] ----
        {
            floatx4 dd0 = (floatx4){0.f, 0.f, 0.f, 0.f};
            floatx4 dd1 = (floatx4){0.f, 0.f, 0.f, 0.f};

            // sub 0: w_local = mrow
            {
                const float* bp = &dwT[i & 1][mrow][q * 8];
                fvec4 alo = *(const fvec4*)(bp);
                fvec4 ahi = *(const fvec4*)(bp + 4);
                fvec4 blo = *(const fvec4*)(bp + 32);
                fvec4 bhi = *(const fvec4*)(bp + 36);
                half8 ha, hb;
                #pragma unroll
                for (int j = 0; j < 4; ++j) {
                    ha[j]     = (_Float16)alo[j];
                    ha[j + 4] = (_Float16)ahi[j];
                    hb[j]     = (_Float16)blo[j];
                    hb[j + 4] = (_Float16)bhi[j];
                }
                dd0 = __builtin_amdgcn_mfma_f32_16x16x32_f16(ha, af0, dd0, 0, 0, 0);
                dd0 = __builtin_amdgcn_mfma_f32_16x16x32_f16(hb, af1, dd0, 0, 0, 0);
            }
            // sub 1: w_local = 16 + mrow
            {
                const float* bp = &dwT[i & 1][16 + mrow][q * 8];
                fvec4 alo = *(const fvec4*)(bp);
                fvec4 ahi = *(const fvec4*)(bp + 4);
                fvec4 blo = *(const fvec4*)(bp + 32);
                fvec4 bhi = *(const fvec4*)(bp + 36);
                half8 ha, hb;
                #pragma unroll
                for (int j = 0; j < 4; ++j) {
                    ha[j]     = (_Float16)alo[j];
                    ha[j + 4] = (_Float16)ahi[j];
                    hb[j]     = (_Float16)blo[j];
                    hb[j + 4] = (_Float16)bhi[j];
                }
                dd1 = __builtin_amdgcn_mfma_f32_16x16x32_f16(ha, af0, dd1, 0, 0, 0);
                dd1 = __builtin_amdgcn_mfma_f32_16x16x32_f16(hb, af1, dd1, 0, 0, 0);
            }

            // D layout: col(k_out) = mrow, row(w) = q*4 + reg  -> float4 stores
            float* op = obase + (size_t)i * WW;
            __builtin_nontemporal_store(dd0, (floatx4*)op);          // w = tw0 + q*4
            __builtin_nontemporal_store(dd1, (floatx4*)(op + 16));   // w = tw0 + 16 + q*4
        }
    }
}

extern "C" void kernel_launch(void* const* d_in, const int* in_sizes, int n_in,
                              void* d_out, int out_size, void* d_ws, size_t ws_size,
                              hipStream_t stream) {
    const float* x    = (const float*)d_in[0];  // [8,64,256,256]
    const float* dwgt = (const float*)d_in[1];  // [64,1,3,3]
    const float* pwgt = (const float*)d_in[2];  // [64,64,1,1]
    const float* attw = (const float*)d_in[3];  // [64,64]
    const float* gatt = (const float*)d_in[4];  // [64,64]
    _Float16* Mh = (_Float16*)d_ws;             // 4096 f16 = 8 KB
    float* o  = (float*)d_out;

    prep_M<<<1, 1024, 0, stream>>>(attw, gatt, pwgt, Mh);

    dim3 grid(WW / TW, HH / ROWS, NB);
    fused_conv_mix<<<grid, 256, 0, stream>>>(x, dwgt, Mh, o);
}